// Round 2
// baseline (153.148 us; speedup 1.0000x reference)
//
#include <hip/hip_runtime.h>
#include <math.h>

// Problem constants (from reference): B=32, S=2048, C=16, E=8, H=16
#define NB 32
#define NS 2048
#define NC 16
#define NE 8
#define NH 16

// ---------------------------------------------------------------------------
// Kernel A: gates.
// g[r,e] = x_row(r) . Wm[e] + bm[e] + softplus(x_row(r) . Wn[e] + bn[e])
// row r = b*16 + c ; x_row elements: x[b, s, c, t] at flat b*65536 + s*32 + c*2 + t
// Then strict top-k mask (g > kth where kth = sorted_ascending[E-k-1]) and
// softmax over survivors; masked entries are EXACT zeros.
// ---------------------------------------------------------------------------
__global__ __launch_bounds__(256) void gate_kernel(
    const float* __restrict__ x,
    const float* __restrict__ Wm, const float* __restrict__ bm,
    const float* __restrict__ Wn, const float* __restrict__ bn,
    const int* __restrict__ kptr,
    float* __restrict__ gates)
{
    const int r = blockIdx.x;           // 0..511
    const int b = r >> 4;
    const int c = r & 15;
    const float* xb = x + b * (NS * NC * 2) + c * 2;

    float am[NE], an[NE];
#pragma unroll
    for (int e = 0; e < NE; ++e) { am[e] = 0.f; an[e] = 0.f; }

    for (int s = threadIdx.x; s < NS; s += 256) {
        const float2 xv = *(const float2*)(xb + s * (NC * 2));
#pragma unroll
        for (int e = 0; e < NE; ++e) {
            const float2 wm = *(const float2*)(Wm + e * (2 * NS) + 2 * s);
            const float2 wn = *(const float2*)(Wn + e * (2 * NS) + 2 * s);
            am[e] += xv.x * wm.x + xv.y * wm.y;
            an[e] += xv.x * wn.x + xv.y * wn.y;
        }
    }

    // wave (64-lane) butterfly reduce
#pragma unroll
    for (int e = 0; e < NE; ++e) {
#pragma unroll
        for (int off = 32; off > 0; off >>= 1) {
            am[e] += __shfl_xor(am[e], off);
            an[e] += __shfl_xor(an[e], off);
        }
    }

    __shared__ float red[4][2 * NE];
    const int wave = threadIdx.x >> 6;
    const int lane = threadIdx.x & 63;
    if (lane == 0) {
#pragma unroll
        for (int e = 0; e < NE; ++e) {
            red[wave][e]      = am[e];
            red[wave][NE + e] = an[e];
        }
    }
    __syncthreads();

    if (threadIdx.x == 0) {
        float g[NE];
#pragma unroll
        for (int e = 0; e < NE; ++e) {
            float gm = red[0][e] + red[1][e] + red[2][e] + red[3][e];
            float gn = red[0][NE + e] + red[1][NE + e] + red[2][NE + e] + red[3][NE + e];
            gn += bn[e];
            float sp = (gn > 20.f) ? gn : log1pf(expf(gn));
            g[e] = gm + bm[e] + sp;
        }
        // insertion sort ascending (8 elems)
        float srt[NE];
#pragma unroll
        for (int e = 0; e < NE; ++e) srt[e] = g[e];
        for (int i = 1; i < NE; ++i) {
            float key = srt[i];
            int j = i - 1;
            while (j >= 0 && srt[j] > key) { srt[j + 1] = srt[j]; --j; }
            srt[j + 1] = key;
        }
        const int k = *kptr;
        const float kth = srt[NE - k - 1];
        const float mx  = srt[NE - 1];
        float gw[NE];
        float denom = 0.f;
#pragma unroll
        for (int e = 0; e < NE; ++e) {
            if (g[e] > kth) { gw[e] = expf(g[e] - mx); denom += gw[e]; }
            else            { gw[e] = 0.f; }
        }
        const float inv = 1.f / denom;
#pragma unroll
        for (int e = 0; e < NE; ++e) gates[r * NE + e] = gw[e] * inv;
    }
}

// ---------------------------------------------------------------------------
// Nonlinearities (expert e uses _NLINS[e]); exact forms matching jax.
// ---------------------------------------------------------------------------
template <int E> __device__ __forceinline__ float nlin(float v);
template <> __device__ __forceinline__ float nlin<0>(float v) { return fmaxf(v, 0.f); }                       // relu
template <> __device__ __forceinline__ float nlin<1>(float v) { return tanhf(v); }                            // tanh
template <> __device__ __forceinline__ float nlin<2>(float v) { return v > 0.f ? v : expm1f(v); }             // elu
template <> __device__ __forceinline__ float nlin<3>(float v) { return v / (1.f + expf(-v)); }                // silu
template <> __device__ __forceinline__ float nlin<4>(float v) { return v; }                                   // none
template <> __device__ __forceinline__ float nlin<5>(float v) { return 0.5f * v * (1.f + erff(v * 0.70710678118654752f)); } // gelu exact
template <> __device__ __forceinline__ float nlin<6>(float v) {                                               // selu
    return 1.0507009873554805f * (v > 0.f ? v : 1.6732632423543772f * expm1f(v));
}
template <> __device__ __forceinline__ float nlin<7>(float v) { return (v > 20.f) ? v : log1pf(expf(v)); }    // softplus

template <int E>
__device__ __forceinline__ void expert_accum(
    float x0, float x1, float amp, float ge,
    const float* __restrict__ W1, const float* __restrict__ b1,
    const float* __restrict__ W2, const float* __restrict__ b2,
    float& ot0, float& ot1)
{
    if (ge != 0.f) {  // wave-uniform branch (gate row shared by whole wave)
        float a0 = b2[E * 2 + 0];
        float a1 = b2[E * 2 + 1];
#pragma unroll
        for (int h = 0; h < NH; ++h) {
            const float* w1 = W1 + (E * NH + h) * 3;
            float pre = w1[0] * x0 + w1[1] * x1 + w1[2] * amp + b1[E * NH + h];
            float a = nlin<E>(pre);
            a0 += W2[E * 2 * NH + h] * a;
            a1 += W2[E * 2 * NH + NH + h] * a;
        }
        ot0 += ge * a0;
        ot1 += ge * a1;
    }
}

// ---------------------------------------------------------------------------
// Kernel B: expert evaluation + gated combine + layout scramble.
// out[b,s,c,t] = sum_e gate[b*16+c, e] * Expert_e( x[b, c*128 + (s>>4), s&15, :] )
// Block = (s_blk, b): covers s in [s_blk*128, s_blk*128+128), all 16 c.
// Wave w (of 16) handles c=w -> gate row wave-uniform.
// Results staged in padded LDS for coalesced float2 global writes.
// ---------------------------------------------------------------------------
__global__ __launch_bounds__(1024) void expert_kernel(
    const float* __restrict__ x,
    const float* __restrict__ W1, const float* __restrict__ b1,
    const float* __restrict__ W2, const float* __restrict__ b2,
    const float* __restrict__ gates,
    float* __restrict__ out)
{
    const int b  = blockIdx.y;
    const int s0 = blockIdx.x * 128;
    const int c    = threadIdx.x >> 6;   // wave id = output column c
    const int lane = threadIdx.x & 63;

    __shared__ float lds[128 * 34];      // [128 s_local][17 float2 slots] (pad col -> 4-way max)

    float g[NE];
    const float* grow = gates + (b * NC + c) * NE;
#pragma unroll
    for (int e = 0; e < NE; ++e) g[e] = grow[e];

#pragma unroll
    for (int jj = 0; jj < 2; ++jj) {
        const int s_local = lane + 64 * jj;
        const int s = s0 + s_local;
        const float2 xv = *(const float2*)(x + b * (NS * NC * 2)
                                             + (c * 128 + (s >> 4)) * (NC * 2)
                                             + (s & 15) * 2);
        const float amp = sqrtf(xv.x * xv.x + xv.y * xv.y);
        float ot0 = 0.f, ot1 = 0.f;
        expert_accum<0>(xv.x, xv.y, amp, g[0], W1, b1, W2, b2, ot0, ot1);
        expert_accum<1>(xv.x, xv.y, amp, g[1], W1, b1, W2, b2, ot0, ot1);
        expert_accum<2>(xv.x, xv.y, amp, g[2], W1, b1, W2, b2, ot0, ot1);
        expert_accum<3>(xv.x, xv.y, amp, g[3], W1, b1, W2, b2, ot0, ot1);
        expert_accum<4>(xv.x, xv.y, amp, g[4], W1, b1, W2, b2, ot0, ot1);
        expert_accum<5>(xv.x, xv.y, amp, g[5], W1, b1, W2, b2, ot0, ot1);
        expert_accum<6>(xv.x, xv.y, amp, g[6], W1, b1, W2, b2, ot0, ot1);
        expert_accum<7>(xv.x, xv.y, amp, g[7], W1, b1, W2, b2, ot0, ot1);
        lds[s_local * 34 + c * 2 + 0] = ot0;
        lds[s_local * 34 + c * 2 + 1] = ot1;
    }
    __syncthreads();

    // coalesced write-back: consecutive threads -> consecutive float2
#pragma unroll
    for (int jj = 0; jj < 2; ++jj) {
        const int m  = threadIdx.x + 1024 * jj;   // float2 index within block tile
        const int sl = m >> 4;
        const int cc = m & 15;
        float2 v = make_float2(lds[sl * 34 + cc * 2], lds[sl * 34 + cc * 2 + 1]);
        *(float2*)(out + b * (NS * NC * 2) + (s0 + sl) * (NC * 2) + cc * 2) = v;
    }
}

extern "C" void kernel_launch(void* const* d_in, const int* in_sizes, int n_in,
                              void* d_out, int out_size, void* d_ws, size_t ws_size,
                              hipStream_t stream) {
    const float* x  = (const float*)d_in[0];
    const float* Wm = (const float*)d_in[1];
    const float* bm = (const float*)d_in[2];
    const float* Wn = (const float*)d_in[3];
    const float* bn = (const float*)d_in[4];
    const float* W1 = (const float*)d_in[5];
    const float* b1 = (const float*)d_in[6];
    const float* W2 = (const float*)d_in[7];
    const float* b2 = (const float*)d_in[8];
    const int*   kp = (const int*)d_in[9];
    float* out   = (float*)d_out;
    float* gates = (float*)d_ws;   // 512 * 8 floats = 16 KB

    gate_kernel<<<NB * NC, 256, 0, stream>>>(x, Wm, bm, Wn, bn, kp, gates);

    dim3 grid(NS / 128, NB);
    expert_kernel<<<grid, 1024, 0, stream>>>(x, W1, b1, W2, b2, gates, out);
}

// Round 6
// 115.468 us; speedup vs baseline: 1.3263x; 1.3263x over previous
//
#include <hip/hip_runtime.h>
#include <math.h>

// Problem constants: B=32, S=2048, C=16, E=8, H=16
#define NB 32
#define NS 2048
#define NC 16
#define NE 8
#define NH 16
#define KSL 16            // K-slices for gate partial GEMM (K = 2*NS = 4096)

// ---------------------------------------------------------------------------
// Kernel A1: gate partial sums.  g_pre[r=(b,c)][e16] = sum_K x2[r][K]*W[e16][K]
// where x2[(b,c)][2s+t] = x[b,s,c,t]; e16<8 -> Wm row, e16>=8 -> Wn row.
// Grid (KSL, NB), 256 thr = 16 e16 x 16 c (c fastest -> coalesced x).
// ---------------------------------------------------------------------------
__global__ __launch_bounds__(256) void gate_partial(
    const float* __restrict__ x,
    const float* __restrict__ Wm,
    const float* __restrict__ Wn,
    float* __restrict__ partial)
{
    const int b  = blockIdx.y;
    const int sl = blockIdx.x;
    const int c  = threadIdx.x & 15;
    const int e  = threadIdx.x >> 4;          // 0..15

    const float* __restrict__ Wrow = (e < 8) ? (Wm + e * (2 * NS))
                                             : (Wn + (e - 8) * (2 * NS));
    const float* __restrict__ xb = x + b * (NS * NC * 2) + c * 2;
    const int s_base = sl * (NS / KSL);       // 128 s per slice

    float acc = 0.f;
#pragma unroll 4
    for (int i = 0; i < NS / KSL; i += 2) {
        const int s = s_base + i;
        const float4 wv = *(const float4*)(Wrow + 2 * s);
        const float2 x0 = *(const float2*)(xb + s * (NC * 2));
        const float2 x1 = *(const float2*)(xb + (s + 1) * (NC * 2));
        acc = fmaf(x0.x, wv.x, acc);
        acc = fmaf(x0.y, wv.y, acc);
        acc = fmaf(x1.x, wv.z, acc);
        acc = fmaf(x1.y, wv.w, acc);
    }
    // layout [b][sl][e][c] so gate_final reads are lane-contiguous in c
    partial[(((b * KSL) + sl) * 16 + e) * 16 + c] = acc;
}

// ---------------------------------------------------------------------------
// Kernel A2: gate finalize. One thread per row r=(b,c): reduce slices,
// g = gm + bm + softplus(gn + bn); strict top-k mask (g > kth) + softmax,
// masked entries EXACT zero.
// ---------------------------------------------------------------------------
__global__ __launch_bounds__(64) void gate_final(
    const float* __restrict__ partial,
    const float* __restrict__ bm, const float* __restrict__ bn,
    const int* __restrict__ kptr,
    float* __restrict__ gates)
{
    const int r = blockIdx.x * 64 + threadIdx.x;   // 0..511
    const int b = r >> 4;
    const int c = r & 15;

    float g16[16];
#pragma unroll
    for (int e = 0; e < 16; ++e) g16[e] = 0.f;
    for (int sl = 0; sl < KSL; ++sl) {
        const float* p = partial + ((b * KSL + sl) * 16) * 16 + c;
#pragma unroll
        for (int e = 0; e < 16; ++e) g16[e] += p[e * 16];
    }

    float g[NE];
#pragma unroll
    for (int e = 0; e < NE; ++e) {
        const float gn = g16[e + 8] + bn[e];
        const float sp = (gn > 20.f) ? gn : __logf(1.f + __expf(gn));
        g[e] = g16[e] + bm[e] + sp;
    }

    // branchless 8-element sorting network (ascending), 19 comparators
    float s[NE];
#pragma unroll
    for (int e = 0; e < NE; ++e) s[e] = g[e];
#define CSWP(i, j) { float lo = fminf(s[i], s[j]); float hi = fmaxf(s[i], s[j]); s[i] = lo; s[j] = hi; }
    CSWP(0,1) CSWP(2,3) CSWP(4,5) CSWP(6,7)
    CSWP(0,2) CSWP(1,3) CSWP(4,6) CSWP(5,7)
    CSWP(1,2) CSWP(5,6)
    CSWP(0,4) CSWP(1,5) CSWP(2,6) CSWP(3,7)
    CSWP(2,4) CSWP(3,5)
    CSWP(1,2) CSWP(3,4) CSWP(5,6)
#undef CSWP

    const int k = *kptr;
    const float kth = s[NE - 1 - k];
    const float mx  = s[NE - 1];
    float gw[NE];
    float denom = 0.f;
#pragma unroll
    for (int e = 0; e < NE; ++e) {
        const float ex = __expf(g[e] - mx);
        const float keep = (g[e] > kth) ? ex : 0.f;
        gw[e] = keep;
        denom += keep;
    }
    const float inv = 1.f / denom;
    float4 o0 = make_float4(gw[0] * inv, gw[1] * inv, gw[2] * inv, gw[3] * inv);
    float4 o1 = make_float4(gw[4] * inv, gw[5] * inv, gw[6] * inv, gw[7] * inv);
    *(float4*)(gates + r * NE)     = o0;
    *(float4*)(gates + r * NE + 4) = o1;
}

// ---------------------------------------------------------------------------
// Fast nonlinearities (native exp/log based; tolerance budget is ~0.335 abs,
// these are all <= ~2e-6 abs err)
// ---------------------------------------------------------------------------
template <int E> __device__ __forceinline__ float nlin(float v);
template <> __device__ __forceinline__ float nlin<0>(float v) { return fmaxf(v, 0.f); }   // relu
template <> __device__ __forceinline__ float nlin<1>(float v) {                           // tanh
    const float t = __expf(2.f * fminf(v, 15.f));
    return __fdividef(t - 1.f, t + 1.f);
}
template <> __device__ __forceinline__ float nlin<2>(float v) {                           // elu
    return v > 0.f ? v : (__expf(v) - 1.f);
}
template <> __device__ __forceinline__ float nlin<3>(float v) {                           // silu
    return __fdividef(v, 1.f + __expf(-v));
}
template <> __device__ __forceinline__ float nlin<4>(float v) { return v; }               // none
template <> __device__ __forceinline__ float nlin<5>(float v) {                           // gelu (erf, A&S 7.1.26)
    const float u  = v * 0.70710678118654752f;
    const float au = fabsf(u);
    const float t  = __fdividef(1.f, fmaf(0.3275911f, au, 1.f));
    float p = fmaf(1.061405429f, t, -1.453152027f);
    p = fmaf(p, t, 1.421413741f);
    p = fmaf(p, t, -0.284496736f);
    p = fmaf(p, t, 0.254829592f);
    const float y = 1.f - p * t * __expf(-u * u);
    const float erfv = copysignf(y, u);
    return 0.5f * v * (1.f + erfv);
}
template <> __device__ __forceinline__ float nlin<6>(float v) {                           // selu
    return 1.0507009873554805f * (v > 0.f ? v : 1.6732632423543772f * (__expf(v) - 1.f));
}
template <> __device__ __forceinline__ float nlin<7>(float v) {                           // softplus
    return (v > 20.f) ? v : __logf(1.f + __expf(v));
}

// Process BOTH per-thread positions inside one gate-guarded block:
// weights loaded once, two independent chains through the transcendental.
template <int E>
__device__ __forceinline__ void expert_accum2(
    const float (&xx)[2], const float (&xy)[2], const float (&am)[2], float ge,
    const float* __restrict__ W1, const float* __restrict__ b1,
    const float* __restrict__ W2, const float* __restrict__ b2,
    float (&ot0)[2], float (&ot1)[2])
{
    if (ge != 0.f) {   // wave-uniform (gate row shared by whole wave) -> execz skip
        float a0[2] = {0.f, 0.f}, a1[2] = {0.f, 0.f};
#pragma unroll
        for (int h = 0; h < NH; ++h) {
            const float w0  = W1[(E * NH + h) * 3 + 0];
            const float w1v = W1[(E * NH + h) * 3 + 1];
            const float w2v = W1[(E * NH + h) * 3 + 2];
            const float bb  = b1[E * NH + h];
            const float u0  = W2[E * 2 * NH + h];
            const float u1  = W2[E * 2 * NH + NH + h];
#pragma unroll
            for (int j = 0; j < 2; ++j) {
                const float pre = fmaf(w0, xx[j], fmaf(w1v, xy[j], fmaf(w2v, am[j], bb)));
                const float a = nlin<E>(pre);
                a0[j] = fmaf(u0, a, a0[j]);
                a1[j] = fmaf(u1, a, a1[j]);
            }
        }
        const float c0 = b2[E * 2 + 0];
        const float c1 = b2[E * 2 + 1];
#pragma unroll
        for (int j = 0; j < 2; ++j) {
            ot0[j] = fmaf(ge, a0[j] + c0, ot0[j]);
            ot1[j] = fmaf(ge, a1[j] + c1, ot1[j]);
        }
    }
}

// ---------------------------------------------------------------------------
// Kernel B: out[b,s,c,t] = sum_e gate[b*16+c,e] * Expert_e(x[b, c*128+(s>>4), s&15, :])
// Block (s_blk, b): s in [s0, s0+128), all 16 c. Wave w handles c=w.
// Padded-LDS staging for coalesced float2 writes.
// ---------------------------------------------------------------------------
__global__ __launch_bounds__(1024) void expert_kernel(
    const float* __restrict__ x,
    const float* __restrict__ W1, const float* __restrict__ b1,
    const float* __restrict__ W2, const float* __restrict__ b2,
    const float* __restrict__ gates,
    float* __restrict__ out)
{
    const int b  = blockIdx.y;
    const int s0 = blockIdx.x * 128;
    const int c    = threadIdx.x >> 6;
    const int lane = threadIdx.x & 63;

    __shared__ float lds[128 * 34];   // [128 s_local][17 float2 slots]

    float g[NE];
    const float* grow = gates + (b * NC + c) * NE;
#pragma unroll
    for (int e = 0; e < NE; ++e) g[e] = grow[e];

    float xx[2], xy[2], am[2], ot0[2] = {0.f, 0.f}, ot1[2] = {0.f, 0.f};
#pragma unroll
    for (int j = 0; j < 2; ++j) {
        const int s = s0 + lane + 64 * j;
        const float2 xv = *(const float2*)(x + b * (NS * NC * 2)
                                             + (c * 128 + (s >> 4)) * (NC * 2)
                                             + (s & 15) * 2);
        xx[j] = xv.x; xy[j] = xv.y;
        am[j] = sqrtf(fmaf(xv.x, xv.x, xv.y * xv.y));
    }

    expert_accum2<0>(xx, xy, am, g[0], W1, b1, W2, b2, ot0, ot1);
    expert_accum2<1>(xx, xy, am, g[1], W1, b1, W2, b2, ot0, ot1);
    expert_accum2<2>(xx, xy, am, g[2], W1, b1, W2, b2, ot0, ot1);
    expert_accum2<3>(xx, xy, am, g[3], W1, b1, W2, b2, ot0, ot1);
    expert_accum2<4>(xx, xy, am, g[4], W1, b1, W2, b2, ot0, ot1);
    expert_accum2<5>(xx, xy, am, g[5], W1, b1, W2, b2, ot0, ot1);
    expert_accum2<6>(xx, xy, am, g[6], W1, b1, W2, b2, ot0, ot1);
    expert_accum2<7>(xx, xy, am, g[7], W1, b1, W2, b2, ot0, ot1);

#pragma unroll
    for (int j = 0; j < 2; ++j) {
        const int sl = lane + 64 * j;
        lds[sl * 34 + c * 2 + 0] = ot0[j];
        lds[sl * 34 + c * 2 + 1] = ot1[j];
    }
    __syncthreads();

#pragma unroll
    for (int j = 0; j < 2; ++j) {
        const int m  = threadIdx.x + 1024 * j;
        const int sl = m >> 4;
        const int cc = m & 15;
        float2 v = make_float2(lds[sl * 34 + cc * 2], lds[sl * 34 + cc * 2 + 1]);
        *(float2*)(out + b * (NS * NC * 2) + (s0 + sl) * (NC * 2) + cc * 2) = v;
    }
}

extern "C" void kernel_launch(void* const* d_in, const int* in_sizes, int n_in,
                              void* d_out, int out_size, void* d_ws, size_t ws_size,
                              hipStream_t stream) {
    const float* x  = (const float*)d_in[0];
    const float* Wm = (const float*)d_in[1];
    const float* bm = (const float*)d_in[2];
    const float* Wn = (const float*)d_in[3];
    const float* bn = (const float*)d_in[4];
    const float* W1 = (const float*)d_in[5];
    const float* b1 = (const float*)d_in[6];
    const float* W2 = (const float*)d_in[7];
    const float* b2 = (const float*)d_in[8];
    const int*   kp = (const int*)d_in[9];
    float* out     = (float*)d_out;
    float* gates   = (float*)d_ws;                        // 512*8 floats   = 16 KB
    float* partial = (float*)d_ws + 4096;                 // 32*16*16*16 fl = 512 KB

    dim3 gp_grid(KSL, NB);
    gate_partial<<<gp_grid, 256, 0, stream>>>(x, Wm, Wn, partial);
    gate_final<<<NB * NC / 64, 64, 0, stream>>>(partial, bm, bn, kp, gates);

    dim3 grid(NS / 128, NB);
    expert_kernel<<<grid, 1024, 0, stream>>>(x, W1, b1, W2, b2, gates, out);
}